// Round 1
// baseline (118.707 us; speedup 1.0000x reference)
//
#include <hip/hip_runtime.h>

#define NROWS 16384
#define MREF 4096
#define NLAYER 8
#define BLOCK 256
#define MCHUNK 1024
#define MCHUNKS (MREF / MCHUNK)

// k(n,m) = exp(-(||a||^2 + ||b||^2 - 2 a.b)) with ||a||^2 = ||b||^2 = 2 exactly
// => exp(2*(a.b) - 4), and a.b = cos(f0-r0)+cos(f1-r1) but we keep the dot4 form
// with sin/cos staged, folding into a single v_exp_f32 via exp2.

__global__ __launch_bounds__(BLOCK) void fused_main(
    const float* __restrict__ x,
    const float* __restrict__ layer_W,
    const float* __restrict__ layer_b,
    const float* __restrict__ layer_scale,
    const float* __restrict__ layer_shift,
    const float* __restrict__ refset,
    float* __restrict__ sums)
{
    __shared__ float4 sref[MCHUNK];

    const int tid = threadIdx.x;
    const int mbase = blockIdx.y * MCHUNK;

    // Stage phi(reference_set) chunk into LDS as (sin r0, sin r1, cos r0, cos r1)
    for (int i = tid; i < MCHUNK; i += BLOCK) {
        const float r0 = refset[(mbase + i) * 2 + 0];
        const float r1 = refset[(mbase + i) * 2 + 1];
        float s0, c0, s1, c1;
        sincosf(r0, &s0, &c0);
        sincosf(r1, &s1, &c1);
        float4 v; v.x = s0; v.y = s1; v.z = c0; v.w = c1;
        sref[i] = v;
    }
    __syncthreads();

    const int n = blockIdx.x * BLOCK + tid;

    // 8-layer chain: h = tanh(h @ W.T + b) * s + t   (params wave-uniform -> s_load)
    float h0 = x[n * 2 + 0];
    float h1 = x[n * 2 + 1];
#pragma unroll
    for (int l = 0; l < NLAYER; ++l) {
        const float w00 = layer_W[l * 4 + 0];
        const float w01 = layer_W[l * 4 + 1];
        const float w10 = layer_W[l * 4 + 2];
        const float w11 = layer_W[l * 4 + 3];
        const float b0 = layer_b[l * 2 + 0];
        const float b1 = layer_b[l * 2 + 1];
        const float s0 = layer_scale[l * 2 + 0];
        const float s1 = layer_scale[l * 2 + 1];
        const float t0 = layer_shift[l * 2 + 0];
        const float t1 = layer_shift[l * 2 + 1];
        const float n0 = fmaf(tanhf(fmaf(h1, w01, fmaf(h0, w00, b0))), s0, t0);
        const float n1 = fmaf(tanhf(fmaf(h1, w11, fmaf(h0, w10, b1))), s1, t1);
        h0 = n0; h1 = n1;
    }

    float sf0, cf0, sf1, cf1;
    sincosf(h0, &sf0, &cf0);
    sincosf(h1, &sf1, &cf1);

    // exp(2*dot - 4) = exp2(dot * 2*log2e - 4*log2e): pre-scale the a-fragment.
    const float L2E2 = 2.0f * 1.4426950408889634f;  // 2*log2(e)
    const float BIAS = 4.0f * 1.4426950408889634f;  // 4*log2(e)
    sf0 *= L2E2; sf1 *= L2E2; cf0 *= L2E2; cf1 *= L2E2;

    float acc = 0.0f;
#pragma unroll 4
    for (int i = 0; i < MCHUNK; ++i) {
        const float4 v = sref[i];  // wave-uniform address -> LDS broadcast, no conflicts
        float d = sf0 * v.x;
        d = fmaf(sf1, v.y, d);
        d = fmaf(cf0, v.z, d);
        d = fmaf(cf1, v.w, d);
        acc += exp2f(d - BIAS);
    }

    atomicAdd(&sums[n], acc);
}

__global__ __launch_bounds__(BLOCK) void epilogue(
    const float* __restrict__ sums,
    const float* __restrict__ W1,
    const float* __restrict__ b1,
    const float* __restrict__ W2,
    const float* __restrict__ b2,
    float* __restrict__ out)
{
    const int n = blockIdx.x * BLOCK + threadIdx.x;
    const float agg = sums[n] * (1.0f / (float)MREF);

    float h[4];
#pragma unroll
    for (int j = 0; j < 4; ++j) {
        h[j] = tanhf(fmaf(agg, W1[j], b1[j]));
    }
    float l0 = b2[0], l1 = b2[1];
#pragma unroll
    for (int j = 0; j < 4; ++j) {
        l0 = fmaf(W2[0 * 4 + j], h[j], l0);
        l1 = fmaf(W2[1 * 4 + j], h[j], l1);
    }
    const float mx = fmaxf(l0, l1);
    const float e0 = __expf(l0 - mx);
    const float e1 = __expf(l1 - mx);
    const float inv = 1.0f / (e0 + e1);
    out[2 * n + 0] = e0 * inv;
    out[2 * n + 1] = e1 * inv;
}

extern "C" void kernel_launch(void* const* d_in, const int* in_sizes, int n_in,
                              void* d_out, int out_size, void* d_ws, size_t ws_size,
                              hipStream_t stream) {
    const float* x           = (const float*)d_in[0];
    const float* layer_W     = (const float*)d_in[1];
    const float* layer_b     = (const float*)d_in[2];
    const float* layer_scale = (const float*)d_in[3];
    const float* layer_shift = (const float*)d_in[4];
    const float* refset      = (const float*)d_in[5];
    const float* W1          = (const float*)d_in[6];
    const float* b1          = (const float*)d_in[7];
    const float* W2          = (const float*)d_in[8];
    const float* b2          = (const float*)d_in[9];
    float* out = (float*)d_out;
    float* sums = (float*)d_ws;

    hipMemsetAsync(d_ws, 0, NROWS * sizeof(float), stream);

    dim3 grid(NROWS / BLOCK, MCHUNKS);
    fused_main<<<grid, BLOCK, 0, stream>>>(x, layer_W, layer_b, layer_scale,
                                           layer_shift, refset, sums);
    epilogue<<<NROWS / BLOCK, BLOCK, 0, stream>>>(sums, W1, b1, W2, b2, out);
}

// Round 2
// 98.325 us; speedup vs baseline: 1.2073x; 1.2073x over previous
//
#include <hip/hip_runtime.h>

#define NROWS 16384
#define MREF 4096
#define NLAYER 8
#define BLOCK 256

#define RPT 4                       // rows per thread in main kernel
#define MCHUNK 128                  // m elements per block
#define MCHUNKS (MREF / MCHUNK)     // 32
#define NSEG (NROWS / RPT)          // 4096: row stride between a thread's rows

// ws layout (floats): sums[16384] | rowc float4[16384] | refc float4[4096]
#define WS_SUMS 0
#define WS_ROWC (NROWS)                  // float4 base index (in float4 units after cast)
#define WS_REFC (NROWS + NROWS * 4)      // float offset of refc

// k(n,m) = exp(2*(a.b) - 4) since ||a||^2 = ||b||^2 = 2 exactly (a=[sin,cos]).
// a-side coeffs pre-scaled by 2*log2(e); accumulate exp2(dot); fold exp(-4)/M
// into the epilogue.

__global__ __launch_bounds__(BLOCK) void prep(
    const float* __restrict__ x,
    const float* __restrict__ layer_W,
    const float* __restrict__ layer_b,
    const float* __restrict__ layer_scale,
    const float* __restrict__ layer_shift,
    const float* __restrict__ refset,
    float* __restrict__ ws)
{
    const int n = blockIdx.x * BLOCK + threadIdx.x;

    // zero the partial-sum accumulator (replaces hipMemsetAsync)
    ws[WS_SUMS + n] = 0.0f;

    // 8-layer chain (params wave-uniform -> scalar loads)
    float h0 = x[n * 2 + 0];
    float h1 = x[n * 2 + 1];
#pragma unroll
    for (int l = 0; l < NLAYER; ++l) {
        const float w00 = layer_W[l * 4 + 0];
        const float w01 = layer_W[l * 4 + 1];
        const float w10 = layer_W[l * 4 + 2];
        const float w11 = layer_W[l * 4 + 3];
        const float b0 = layer_b[l * 2 + 0];
        const float b1 = layer_b[l * 2 + 1];
        const float s0 = layer_scale[l * 2 + 0];
        const float s1 = layer_scale[l * 2 + 1];
        const float t0 = layer_shift[l * 2 + 0];
        const float t1 = layer_shift[l * 2 + 1];
        const float n0 = fmaf(tanhf(fmaf(h1, w01, fmaf(h0, w00, b0))), s0, t0);
        const float n1 = fmaf(tanhf(fmaf(h1, w11, fmaf(h0, w10, b1))), s1, t1);
        h0 = n0; h1 = n1;
    }

    float sf0, cf0, sf1, cf1;
    sincosf(h0, &sf0, &cf0);
    sincosf(h1, &sf1, &cf1);

    const float L2E2 = 2.0f * 1.4426950408889634f;  // 2*log2(e)
    float4* rowc = (float4*)(ws + WS_SUMS) + WS_ROWC / 4;  // == (float4*)&ws[NROWS]... keep simple below
    rowc = (float4*)&ws[NROWS];
    float4 rc; rc.x = sf0 * L2E2; rc.y = sf1 * L2E2; rc.z = cf0 * L2E2; rc.w = cf1 * L2E2;
    rowc[n] = rc;

    if (n < MREF) {
        const float r0 = refset[n * 2 + 0];
        const float r1 = refset[n * 2 + 1];
        float s0, c0, s1, c1;
        sincosf(r0, &s0, &c0);
        sincosf(r1, &s1, &c1);
        float4* refc = (float4*)&ws[WS_REFC];
        float4 v; v.x = s0; v.y = s1; v.z = c0; v.w = c1;
        refc[n] = v;
    }
}

__global__ __launch_bounds__(BLOCK) void pair_sum(float* __restrict__ ws)
{
    __shared__ float4 sref[MCHUNK];

    const int tid = threadIdx.x;
    const int mbase = blockIdx.y * MCHUNK;

    const float4* __restrict__ refc = (const float4*)&ws[WS_REFC];
    const float4* __restrict__ rowc = (const float4*)&ws[NROWS];
    float* __restrict__ sums = ws + WS_SUMS;

    if (tid < MCHUNK) sref[tid] = refc[mbase + tid];

    const int base = blockIdx.x * BLOCK + tid;  // [0, NSEG)

    float4 c0 = rowc[base + 0 * NSEG];
    float4 c1 = rowc[base + 1 * NSEG];
    float4 c2 = rowc[base + 2 * NSEG];
    float4 c3 = rowc[base + 3 * NSEG];

    __syncthreads();

    float a0 = 0.0f, a1 = 0.0f, a2 = 0.0f, a3 = 0.0f;
#pragma unroll 4
    for (int i = 0; i < MCHUNK; ++i) {
        const float4 v = sref[i];  // wave-uniform -> LDS broadcast
        float d0 = c0.x * v.x; d0 = fmaf(c0.y, v.y, d0); d0 = fmaf(c0.z, v.z, d0); d0 = fmaf(c0.w, v.w, d0);
        float d1 = c1.x * v.x; d1 = fmaf(c1.y, v.y, d1); d1 = fmaf(c1.z, v.z, d1); d1 = fmaf(c1.w, v.w, d1);
        float d2 = c2.x * v.x; d2 = fmaf(c2.y, v.y, d2); d2 = fmaf(c2.z, v.z, d2); d2 = fmaf(c2.w, v.w, d2);
        float d3 = c3.x * v.x; d3 = fmaf(c3.y, v.y, d3); d3 = fmaf(c3.z, v.z, d3); d3 = fmaf(c3.w, v.w, d3);
        a0 += exp2f(d0);
        a1 += exp2f(d1);
        a2 += exp2f(d2);
        a3 += exp2f(d3);
    }

    atomicAdd(&sums[base + 0 * NSEG], a0);
    atomicAdd(&sums[base + 1 * NSEG], a1);
    atomicAdd(&sums[base + 2 * NSEG], a2);
    atomicAdd(&sums[base + 3 * NSEG], a3);
}

__global__ __launch_bounds__(BLOCK) void epilogue(
    const float* __restrict__ ws,
    const float* __restrict__ W1,
    const float* __restrict__ b1,
    const float* __restrict__ W2,
    const float* __restrict__ b2,
    float* __restrict__ out)
{
    const int n = blockIdx.x * BLOCK + threadIdx.x;
    // mean of exp(2*dot-4) = sums[n] * exp(-4) / M
    const float C = 1.8315638888734179e-2f / (float)MREF;  // exp(-4)/M
    const float agg = ws[WS_SUMS + n] * C;

    float h[4];
#pragma unroll
    for (int j = 0; j < 4; ++j) {
        h[j] = tanhf(fmaf(agg, W1[j], b1[j]));
    }
    float l0 = b2[0], l1 = b2[1];
#pragma unroll
    for (int j = 0; j < 4; ++j) {
        l0 = fmaf(W2[0 * 4 + j], h[j], l0);
        l1 = fmaf(W2[1 * 4 + j], h[j], l1);
    }
    const float mx = fmaxf(l0, l1);
    const float e0 = __expf(l0 - mx);
    const float e1 = __expf(l1 - mx);
    const float inv = 1.0f / (e0 + e1);
    out[2 * n + 0] = e0 * inv;
    out[2 * n + 1] = e1 * inv;
}

extern "C" void kernel_launch(void* const* d_in, const int* in_sizes, int n_in,
                              void* d_out, int out_size, void* d_ws, size_t ws_size,
                              hipStream_t stream) {
    const float* x           = (const float*)d_in[0];
    const float* layer_W     = (const float*)d_in[1];
    const float* layer_b     = (const float*)d_in[2];
    const float* layer_scale = (const float*)d_in[3];
    const float* layer_shift = (const float*)d_in[4];
    const float* refset      = (const float*)d_in[5];
    const float* W1          = (const float*)d_in[6];
    const float* b1          = (const float*)d_in[7];
    const float* W2          = (const float*)d_in[8];
    const float* b2          = (const float*)d_in[9];
    float* out = (float*)d_out;
    float* ws  = (float*)d_ws;

    prep<<<NROWS / BLOCK, BLOCK, 0, stream>>>(x, layer_W, layer_b, layer_scale,
                                              layer_shift, refset, ws);

    dim3 grid(NSEG / BLOCK, MCHUNKS);  // 16 x 32 = 512 blocks
    pair_sum<<<grid, BLOCK, 0, stream>>>(ws);

    epilogue<<<NROWS / BLOCK, BLOCK, 0, stream>>>(ws, W1, b1, W2, b2, out);
}